// Round 6
// baseline (284.578 us; speedup 1.0000x reference)
//
#include <hip/hip_runtime.h>
#include <math.h>

// EdgeDetection: fused gray -> gauss3x3(sigma=0.8) -> scharr -> L2 mag, reflect-101
// R5: wave-streaming, 512-px strips, 8 px/lane. Vertical-first separable composite
// (Gauss∘Scharr 5-taps, same math as R2-R4 which passed). 12-wide gray ring in
// registers holds halo columns, so the output stage needs no shuffles. Halo loads
// only 3 of 9 VMEM/row. Nontemporal output stores keep L2 for input halo reuse.

#define IMG_H 1024
#define IMG_W 1024
#define SW 512           // strip width: 64 lanes * 8 px
#define SH 4             // output rows per wave
#define NROWS (SH + 4)

// 1D gaussian sigma=0.8 k=3: e=exp(-0.78125); W0=1/(1+2e), W1=e/(1+2e)
#define W0 0.52201125f
#define W1 0.23899437f
// composite smooth a = conv([3,10,3],[W1,W0,W1]):
#define AV0 0.71698311f   // 3*W1
#define AV1 3.95597745f   // 3*W0 + 10*W1
#define AV2 6.65407872f   // 10*W0 + 6*W1
// composite deriv d = conv([-1,0,1],[W1,W0,W1]) = [-W1,-W0,0,W0,W1]

typedef float v4f __attribute__((ext_vector_type(4)));

__device__ __forceinline__ float4 gray4(float4 r, float4 g, float4 b) {
    float4 o;
    o.x = 0.299f * r.x + 0.587f * g.x + 0.114f * b.x;
    o.y = 0.299f * r.y + 0.587f * g.y + 0.114f * b.y;
    o.z = 0.299f * r.z + 0.587f * g.z + 0.114f * b.z;
    o.w = 0.299f * r.w + 0.587f * g.w + 0.114f * b.w;
    return o;
}

__device__ __forceinline__ void ntstore4(float* p, float a, float b, float c, float d) {
    v4f v = {a, b, c, d};
    __builtin_nontemporal_store(v, (v4f*)p);
}

__global__ __launch_bounds__(256, 4)
void edge_kernel(const float* __restrict__ in, float* __restrict__ out, int B) {
    const int tid  = threadIdx.x;
    const int lane = tid & 63;
    const int gw   = blockIdx.x * 4 + (tid >> 6);

    // low bits = ys so co-resident waves share vertical halo rows in cache
    const int ys = gw & 255;              // 256 strips of SH=4 rows
    const int xs = (gw >> 8) & 1;         // 2 strips across
    const int b  = gw >> 9;

    const int x0 = xs * SW;
    const int y0 = ys * SH;
    const int cb = x0 + 8 * lane;

    const size_t plane = (size_t)IMG_H * IMG_W;
    const float* pr  = in + (size_t)b * 3 * plane;
    const float* pg  = pr + plane;
    const float* pbl = pg + plane;
    float* po = out + (size_t)b * 3 * plane;

    // halo float4: lane0 -> left (x0-4), lanes>=1 -> right (x0+SW) [uniform]
    int hx = (lane == 0) ? (x0 - 4) : (x0 + SW);
    hx = min(max(hx, 0), IMG_W - 4);

    float ring[5][12];

    #pragma unroll
    for (int t = 0; t < NROWS; ++t) {
        int yy = y0 - 2 + t;
        yy = (yy < 0) ? -yy : ((yy >= IMG_H) ? (2 * IMG_H - 2 - yy) : yy);
        const size_t ro = (size_t)yy << 10;

        float4 ra = *(const float4*)(pr  + ro + cb);
        float4 rb = *(const float4*)(pr  + ro + cb + 4);
        float4 ga = *(const float4*)(pg  + ro + cb);
        float4 gb = *(const float4*)(pg  + ro + cb + 4);
        float4 ba = *(const float4*)(pbl + ro + cb);
        float4 bb = *(const float4*)(pbl + ro + cb + 4);
        float4 hr = *(const float4*)(pr  + ro + hx);
        float4 hg = *(const float4*)(pg  + ro + hx);
        float4 hb = *(const float4*)(pbl + ro + hx);

        float4 gA  = gray4(ra, ga, ba);   // px 8i .. 8i+3
        float4 gB  = gray4(rb, gb, bb);   // px 8i+4 .. 8i+7
        float4 hgr = gray4(hr, hg, hb);

        // 12-wide window: W[0..11] = gray at px (cb-2) .. (cb+9)
        float w0  = __shfl_up(gB.z, 1);
        float w1  = __shfl_up(gB.w, 1);
        float w10 = __shfl_down(gA.x, 1);
        float w11 = __shfl_down(gA.y, 1);
        if (lane == 0) {
            w0 = (xs == 0) ? gA.z : hgr.z;   // px -2 -> reflect px2 | halo
            w1 = (xs == 0) ? gA.y : hgr.w;   // px -1 -> reflect px1 | halo
        }
        if (lane == 63) {
            w10 = (xs == 1) ? gB.z : hgr.x;  // px 1024 -> reflect 1022 | halo
            w11 = (xs == 1) ? gB.y : hgr.y;  // px 1025 -> reflect 1021 | halo
        }

        const int ri = t % 5;
        ring[ri][0]  = w0;   ring[ri][1]  = w1;
        ring[ri][2]  = gA.x; ring[ri][3]  = gA.y;
        ring[ri][4]  = gA.z; ring[ri][5]  = gA.w;
        ring[ri][6]  = gB.x; ring[ri][7]  = gB.y;
        ring[ri][8]  = gB.z; ring[ri][9]  = gB.w;
        ring[ri][10] = w10;  ring[ri][11] = w11;

        if (t >= 4) {
            const int r0 = (t+1) % 5, r1 = (t+2) % 5, r2 = (t+3) % 5,
                      r3 = (t+4) % 5, r4 = t % 5;
            float vs[12], vd[12];
            #pragma unroll
            for (int c = 0; c < 12; ++c) {
                vs[c] = AV0 * (ring[r0][c] + ring[r4][c])
                      + AV1 * (ring[r1][c] + ring[r3][c])
                      + AV2 *  ring[r2][c];
                vd[c] = W1 * (ring[r4][c] - ring[r0][c])
                      + W0 * (ring[r3][c] - ring[r1][c]);
            }
            float m[8];
            #pragma unroll
            for (int k = 0; k < 8; ++k) {
                float sx = W1 * (vs[k+4] - vs[k]) + W0 * (vs[k+3] - vs[k+1]);
                float sy = AV0 * (vd[k] + vd[k+4]) + AV1 * (vd[k+1] + vd[k+3])
                         + AV2 * vd[k+2];
                m[k] = sqrtf(sx * sx + sy * sy);
            }
            size_t o = ((size_t)(y0 + t - 4) << 10) + cb;
            ntstore4(po + o,                 m[0], m[1], m[2], m[3]);
            ntstore4(po + o + 4,             m[4], m[5], m[6], m[7]);
            ntstore4(po + o + plane,         m[0], m[1], m[2], m[3]);
            ntstore4(po + o + plane + 4,     m[4], m[5], m[6], m[7]);
            ntstore4(po + o + 2 * plane,     m[0], m[1], m[2], m[3]);
            ntstore4(po + o + 2 * plane + 4, m[4], m[5], m[6], m[7]);
        }
    }
}

extern "C" void kernel_launch(void* const* d_in, const int* in_sizes, int n_in,
                              void* d_out, int out_size, void* d_ws, size_t ws_size,
                              hipStream_t stream) {
    const float* in = (const float*)d_in[0];
    float* out = (float*)d_out;
    const int B = in_sizes[0] / (3 * IMG_H * IMG_W);
    // waves: 2 xs * 256 ys * B; 4 waves per block
    const int nblocks = (2 * 256 * B) / 4;
    edge_kernel<<<dim3(nblocks), dim3(256), 0, stream>>>(in, out, B);
}

// Round 7
// 195.363 us; speedup vs baseline: 1.4567x; 1.4567x over previous
//
#include <hip/hip_runtime.h>
#include <math.h>

// EdgeDetection: fused gray -> gauss3x3(sigma=0.8) -> scharr -> L2 mag, reflect-101
// R6: full-row waves. One wave = 2 output rows of 1024 px (16 px/lane via 4
// contiguous 256-px segments -> every VMEM instr is a dense 1KB wave access,
// 4KB runs per channel). 6 input rows stream through dual (sx,sy) accumulators
// for the 2 output rows. No LDS, no barriers, no halo loads. XCD banding: each
// XCD owns one image so vertical re-reads hit its L2.

#define IMG_H 1024
#define IMG_W 1024

// 1D gaussian sigma=0.8 k=3: e=exp(-0.78125); W0=1/(1+2e), W1=e/(1+2e)
#define W0f 0.52201125f
#define W1f 0.23899437f
// composite smooth a = conv([3,10,3],[W1,W0,W1]) (5-tap, symmetric):
#define AV0 0.71698311f   // 3*W1
#define AV1 3.95597745f   // 3*W0 + 10*W1
#define AV2 6.65407872f   // 10*W0 + 6*W1
// composite deriv d = conv([-1,0,1],[W1,W0,W1]) = [-W1,-W0,0,W0,W1]

__device__ __forceinline__ float4 gray4(float4 r, float4 g, float4 b) {
    float4 o;
    o.x = 0.299f * r.x + 0.587f * g.x + 0.114f * b.x;
    o.y = 0.299f * r.y + 0.587f * g.y + 0.114f * b.y;
    o.z = 0.299f * r.z + 0.587f * g.z + 0.114f * b.z;
    o.w = 0.299f * r.w + 0.587f * g.w + 0.114f * b.w;
    return o;
}

__global__ __launch_bounds__(256, 3)
void edge_kernel(const float* __restrict__ in, float* __restrict__ out, int B) {
    const int tid  = threadIdx.x;
    const int lane = tid & 63;
    const int wv   = tid >> 6;

    // XCD banding: gridDim = B*128 blocks; XCD x gets a contiguous range of ids.
    int g  = blockIdx.x;
    int nb = gridDim.x;
    int id = g;
    if ((nb & 7) == 0) {
        int per = nb >> 3;
        id = (g & 7) * per + (g >> 3);
    }
    const int b  = id >> 7;                          // image index (128 blocks/image)
    const int y0 = ((id & 127) << 3) + (wv << 1);    // wave's first output row

    const size_t plane = (size_t)IMG_H * IMG_W;
    const float* pr  = in + (size_t)b * 3 * plane;
    const float* pg  = pr + plane;
    const float* pbl = pg + plane;
    float* po = out + (size_t)b * 3 * plane;

    const int c0 = lane << 2;   // lane base col within each 256-px segment

    float ax0[4][4] = {}, ay0[4][4] = {}, ax1[4][4] = {}, ay1[4][4] = {};

    #pragma unroll
    for (int t = 0; t < 6; ++t) {
        int yy = y0 - 2 + t;
        yy = (yy < 0) ? -yy : ((yy >= IMG_H) ? (2 * IMG_H - 2 - yy) : yy);
        const size_t ro = (size_t)yy << 10;

        float4 gs[4];
        {
            float4 R[4], G[4], Bv[4];
            #pragma unroll
            for (int s = 0; s < 4; ++s) {
                const int off = (s << 8) + c0;
                R[s]  = *(const float4*)(pr  + ro + off);
                G[s]  = *(const float4*)(pg  + ro + off);
                Bv[s] = *(const float4*)(pbl + ro + off);
            }
            #pragma unroll
            for (int s = 0; s < 4; ++s) gs[s] = gray4(R[s], G[s], Bv[s]);
        }

        #pragma unroll
        for (int s = 0; s < 4; ++s) {
            float lm2 = __shfl_up(gs[s].z, 1);     // px c-2
            float lm1 = __shfl_up(gs[s].w, 1);     // px c-1
            float rp1 = __shfl_down(gs[s].x, 1);   // px c+4
            float rp2 = __shfl_down(gs[s].y, 1);   // px c+5
            float bl2, bl1, br0, br1;
            if (s == 0) { bl2 = gs[0].z; bl1 = gs[0].y; }                       // reflect101 at x=0
            else        { bl2 = __shfl(gs[s-1].z, 63); bl1 = __shfl(gs[s-1].w, 63); }
            if (s == 3) { br0 = gs[3].z; br1 = gs[3].y; }                       // reflect101 at x=1023
            else        { br0 = __shfl(gs[s+1].x, 0);  br1 = __shfl(gs[s+1].y, 0); }
            lm2 = (lane == 0)  ? bl2 : lm2;
            lm1 = (lane == 0)  ? bl1 : lm1;
            rp1 = (lane == 63) ? br0 : rp1;
            rp2 = (lane == 63) ? br1 : rp2;

            const float Gw[8] = {lm2, lm1, gs[s].x, gs[s].y, gs[s].z, gs[s].w, rp1, rp2};
            #pragma unroll
            for (int k = 0; k < 4; ++k) {
                float hs = AV0 * (Gw[k] + Gw[k+4]) + AV1 * (Gw[k+1] + Gw[k+3]) + AV2 * Gw[k+2];
                float hd = W1f * (Gw[k+4] - Gw[k]) + W0f * (Gw[k+3] - Gw[k+1]);
                if (t < 5) {   // contributes to output row y0 (offset t-2)
                    const float av = (t == 0 || t == 4) ? AV0 : ((t == 1 || t == 3) ? AV1 : AV2);
                    ax0[s][k] += av * hd;
                    if (t != 2) {
                        const float dv = (t == 0) ? -W1f : (t == 1) ? -W0f : (t == 3) ? W0f : W1f;
                        ay0[s][k] += dv * hs;
                    }
                }
                if (t >= 1) {  // contributes to output row y0+1 (offset t-3)
                    const int u = t - 1;
                    const float av = (u == 0 || u == 4) ? AV0 : ((u == 1 || u == 3) ? AV1 : AV2);
                    ax1[s][k] += av * hd;
                    if (u != 2) {
                        const float dv = (u == 0) ? -W1f : (u == 1) ? -W0f : (u == 3) ? W0f : W1f;
                        ay1[s][k] += dv * hs;
                    }
                }
            }
        }
    }

    // epilogue: magnitude + 3-channel stores for rows y0 and y0+1
    #pragma unroll
    for (int s = 0; s < 4; ++s) {
        float4 m0, m1;
        float* p0 = &m0.x;
        float* p1 = &m1.x;
        #pragma unroll
        for (int k = 0; k < 4; ++k) {
            p0[k] = sqrtf(ax0[s][k] * ax0[s][k] + ay0[s][k] * ay0[s][k]);
            p1[k] = sqrtf(ax1[s][k] * ax1[s][k] + ay1[s][k] * ay1[s][k]);
        }
        const size_t o0 = ((size_t)y0 << 10) + (s << 8) + c0;
        const size_t o1 = o0 + IMG_W;
        *(float4*)(po + o0)              = m0;
        *(float4*)(po + o0 + plane)      = m0;
        *(float4*)(po + o0 + 2 * plane)  = m0;
        *(float4*)(po + o1)              = m1;
        *(float4*)(po + o1 + plane)      = m1;
        *(float4*)(po + o1 + 2 * plane)  = m1;
    }
}

extern "C" void kernel_launch(void* const* d_in, const int* in_sizes, int n_in,
                              void* d_out, int out_size, void* d_ws, size_t ws_size,
                              hipStream_t stream) {
    const float* in = (const float*)d_in[0];
    float* out = (float*)d_out;
    const int B = in_sizes[0] / (3 * IMG_H * IMG_W);
    // one wave per 2 rows: B * 512 waves, 4 waves/block -> B*128 blocks
    const int nblocks = B * 128;
    edge_kernel<<<dim3(nblocks), dim3(256), 0, stream>>>(in, out, B);
}